// Round 1
// baseline (444.699 us; speedup 1.0000x reference)
//
#include <hip/hip_runtime.h>
#include <hip/hip_bf16.h>

#define HEADS 4
#define C 32
#define OUTCH 128   // HEADS*C
#define INCH 128
#define NEG_SLOPE 0.2f

// ---------------------------------------------------------------------------
// CSR construction
// ---------------------------------------------------------------------------
__global__ void k_count(const int* __restrict__ dst, int* __restrict__ deg, int E) {
    int e = blockIdx.x * 256 + threadIdx.x;
    if (e < E) atomicAdd(&deg[dst[e]], 1);
}

// per-block inclusive scan of 1024-element tiles
__global__ __launch_bounds__(1024) void k_scan1(const int* __restrict__ deg,
                                                int* __restrict__ incl,
                                                int* __restrict__ bsum, int n) {
    __shared__ int sm[1024];
    int t = threadIdx.x;
    int g = blockIdx.x * 1024 + t;
    int v = (g < n) ? deg[g] : 0;
    sm[t] = v;
    __syncthreads();
    for (int off = 1; off < 1024; off <<= 1) {
        int add = (t >= off) ? sm[t - off] : 0;
        __syncthreads();
        sm[t] += add;
        __syncthreads();
    }
    if (g < n) incl[g] = sm[t];
    if (t == 1023) bsum[blockIdx.x] = sm[t];
}

// exclusive scan of <=64 block sums (one wave)
__global__ void k_scan2(int* __restrict__ bsum, int nb) {
    int t = threadIdx.x;  // 64 threads
    int v = (t < nb) ? bsum[t] : 0;
    int orig = v;
    for (int off = 1; off < 64; off <<= 1) {
        int u = __shfl_up(v, off);
        if (t >= off) v += u;
    }
    if (t < nb) bsum[t] = v - orig;  // exclusive
}

__global__ __launch_bounds__(1024) void k_scan3(const int* __restrict__ incl,
                                                const int* __restrict__ bsumx,
                                                const int* __restrict__ deg,
                                                int* __restrict__ offs,
                                                int* __restrict__ cursor, int n) {
    int g = blockIdx.x * 1024 + threadIdx.x;
    if (g < n) {
        int excl = incl[g] + bsumx[blockIdx.x] - deg[g];
        offs[g] = excl;
        cursor[g] = excl;
    }
}

__global__ void k_fill(const int* __restrict__ src, const int* __restrict__ dst,
                       int* __restrict__ cursor, int* __restrict__ srcl, int E) {
    int e = blockIdx.x * 256 + threadIdx.x;
    if (e < E) {
        int dn = dst[e];
        int pos = atomicAdd(&cursor[dn], 1);
        srcl[pos] = src[e];
    }
}

// ---------------------------------------------------------------------------
// h = x @ W   (f32, 64-row tile per block, W streamed through L1/L2)
// ---------------------------------------------------------------------------
__global__ __launch_bounds__(256) void k_gemm(const float* __restrict__ x,
                                              const float* __restrict__ W,
                                              float* __restrict__ h, int n) {
    __shared__ float xs[64][128];
    int t = threadIdx.x;
    int rowBase = blockIdx.x * 64;
    // stage x tile: 64 rows x 128 cols = 2048 float4
    for (int i = t; i < 64 * 32; i += 256) {
        int r = i >> 5, c4 = i & 31;
        float4 v = {0.f, 0.f, 0.f, 0.f};
        if (rowBase + r < n)
            v = *(const float4*)(x + (size_t)(rowBase + r) * INCH + c4 * 4);
        *(float4*)&xs[r][c4 * 4] = v;
    }
    __syncthreads();

    int colg = t & 31;   // 32 groups of 4 output cols
    int rowg = t >> 5;   // 8 groups of 8 rows
    float acc[8][4] = {};
    const float4* W4 = (const float4*)W;
    for (int k = 0; k < 128; ++k) {
        float4 w = W4[k * 32 + colg];
#pragma unroll
        for (int i = 0; i < 8; ++i) {
            float xv = xs[rowg * 8 + i][k];
            acc[i][0] = fmaf(xv, w.x, acc[i][0]);
            acc[i][1] = fmaf(xv, w.y, acc[i][1]);
            acc[i][2] = fmaf(xv, w.z, acc[i][2]);
            acc[i][3] = fmaf(xv, w.w, acc[i][3]);
        }
    }
#pragma unroll
    for (int i = 0; i < 8; ++i) {
        int r = rowBase + rowg * 8 + i;
        if (r < n)
            *(float4*)(h + (size_t)r * OUTCH + colg * 4) = *(float4*)acc[i];
    }
}

// ---------------------------------------------------------------------------
// per-node attention logits: a_src[n,h] = <h[n,h,:], att_src[h,:]>, same for dst
// ---------------------------------------------------------------------------
__global__ __launch_bounds__(256) void k_logits(const float* __restrict__ h,
                                                const float* __restrict__ att_src,
                                                const float* __restrict__ att_dst,
                                                float* __restrict__ a_src,
                                                float* __restrict__ a_dst, int n) {
    int t = blockIdx.x * 256 + threadIdx.x;
    int i = t >> 2, head = t & 3;
    if (i >= n) return;
    const float4* hv = (const float4*)(h + (size_t)i * OUTCH + head * C);
    const float4* as4 = (const float4*)(att_src + head * C);
    const float4* ad4 = (const float4*)(att_dst + head * C);
    float ssum = 0.f, dsum = 0.f;
#pragma unroll
    for (int j = 0; j < 8; ++j) {
        float4 v = hv[j], a = as4[j], b = ad4[j];
        ssum += v.x * a.x + v.y * a.y + v.z * a.z + v.w * a.w;
        dsum += v.x * b.x + v.y * b.y + v.z * b.z + v.w * b.w;
    }
    a_src[(size_t)i * 4 + head] = ssum;
    a_dst[(size_t)i * 4 + head] = dsum;
}

// ---------------------------------------------------------------------------
// aggregation: one wave per destination node. Fused softmax-denominator and
// weighted sum (divide once at the end). Self-loop folded in analytically.
// lane -> channels (2*lane, 2*lane+1); head = lane>>4.
// ---------------------------------------------------------------------------
__global__ __launch_bounds__(256) void k_aggr(const float* __restrict__ h,
                                              const float* __restrict__ a_src,
                                              const float* __restrict__ a_dst,
                                              const int* __restrict__ offs,
                                              const int* __restrict__ deg,
                                              const int* __restrict__ srcl,
                                              const float* __restrict__ bias,
                                              float* __restrict__ out, int n) {
    int w = (blockIdx.x * 256 + threadIdx.x) >> 6;
    if (w >= n) return;
    int lane = threadIdx.x & 63;
    int head = lane >> 4;
    int ch = lane << 1;

    float adst = a_dst[(size_t)w * 4 + head];
    // self loop
    float al = a_src[(size_t)w * 4 + head] + adst;
    al = al > 0.f ? al : NEG_SLOPE * al;
    float ex = __expf(al);
    float2 hv = *(const float2*)(h + (size_t)w * OUTCH + ch);
    float denom = ex;
    float acc0 = ex * hv.x, acc1 = ex * hv.y;

    int start = offs[w], d = deg[w];
    int e = 0;
    for (; e + 2 <= d; e += 2) {
        int s0 = srcl[start + e];
        int s1 = srcl[start + e + 1];
        float as0 = a_src[(size_t)s0 * 4 + head];
        float as1 = a_src[(size_t)s1 * 4 + head];
        float2 h0 = *(const float2*)(h + (size_t)s0 * OUTCH + ch);
        float2 h1 = *(const float2*)(h + (size_t)s1 * OUTCH + ch);
        float b0 = as0 + adst; b0 = b0 > 0.f ? b0 : NEG_SLOPE * b0;
        float b1 = as1 + adst; b1 = b1 > 0.f ? b1 : NEG_SLOPE * b1;
        float e0 = __expf(b0), e1 = __expf(b1);
        denom += e0 + e1;
        acc0 = fmaf(e0, h0.x, acc0); acc1 = fmaf(e0, h0.y, acc1);
        acc0 = fmaf(e1, h1.x, acc0); acc1 = fmaf(e1, h1.y, acc1);
    }
    if (e < d) {
        int s0 = srcl[start + e];
        float as0 = a_src[(size_t)s0 * 4 + head];
        float2 h0 = *(const float2*)(h + (size_t)s0 * OUTCH + ch);
        float b0 = as0 + adst; b0 = b0 > 0.f ? b0 : NEG_SLOPE * b0;
        float e0 = __expf(b0);
        denom += e0;
        acc0 = fmaf(e0, h0.x, acc0); acc1 = fmaf(e0, h0.y, acc1);
    }
    float inv = 1.0f / denom;
    out[(size_t)w * OUTCH + ch]     = acc0 * inv + bias[ch];
    out[(size_t)w * OUTCH + ch + 1] = acc1 * inv + bias[ch + 1];
}

// ---------------------------------------------------------------------------
extern "C" void kernel_launch(void* const* d_in, const int* in_sizes, int n_in,
                              void* d_out, int out_size, void* d_ws, size_t ws_size,
                              hipStream_t stream) {
    const float* x       = (const float*)d_in[0];
    const int*   edge    = (const int*)d_in[1];
    const float* W       = (const float*)d_in[2];
    const float* att_src = (const float*)d_in[3];
    const float* att_dst = (const float*)d_in[4];
    const float* bias    = (const float*)d_in[5];
    float* out = (float*)d_out;

    const int N = in_sizes[0] / INCH;
    const int E = in_sizes[1] / 2;
    const int* esrc = edge;
    const int* edst = edge + E;

    // workspace layout (256B aligned)
    auto align = [](size_t v) { return (v + 255) & ~(size_t)255; };
    char* p = (char*)d_ws;
    float* h      = (float*)p; p += align((size_t)N * OUTCH * 4);
    float* a_src  = (float*)p; p += align((size_t)N * 4 * 4);
    float* a_dst  = (float*)p; p += align((size_t)N * 4 * 4);
    int*   deg    = (int*)p;   p += align((size_t)N * 4);
    int*   incl   = (int*)p;   p += align((size_t)N * 4);
    int*   offs   = (int*)p;   p += align((size_t)N * 4);
    int*   cursor = (int*)p;   p += align((size_t)N * 4);
    int*   bsum   = (int*)p;   p += align(64 * 4);
    int*   srcl   = (int*)p;   p += align((size_t)E * 4);

    const int SB = (N + 1023) / 1024;  // scan blocks

    hipMemsetAsync(deg, 0, (size_t)N * 4, stream);
    k_count<<<(E + 255) / 256, 256, 0, stream>>>(edst, deg, E);
    k_scan1<<<SB, 1024, 0, stream>>>(deg, incl, bsum, N);
    k_scan2<<<1, 64, 0, stream>>>(bsum, SB);
    k_scan3<<<SB, 1024, 0, stream>>>(incl, bsum, deg, offs, cursor, N);
    k_fill<<<(E + 255) / 256, 256, 0, stream>>>(esrc, edst, cursor, srcl, E);

    k_gemm<<<(N + 63) / 64, 256, 0, stream>>>(x, W, h, N);
    k_logits<<<(N * 4 + 255) / 256, 256, 0, stream>>>(h, att_src, att_dst, a_src, a_dst, N);
    k_aggr<<<(N + 3) / 4, 256, 0, stream>>>(h, a_src, a_dst, offs, deg, srcl, bias, out, N);
}